// Round 1
// baseline (151.843 us; speedup 1.0000x reference)
//
#include <hip/hip_runtime.h>
#include <hip/hip_bf16.h>
#include <stdint.h>

typedef __attribute__((ext_vector_type(8))) short short8;
typedef __attribute__((ext_vector_type(4))) float floatx4;

static __device__ __forceinline__ ushort f2bf(float f) {
  union { float f; uint32_t u; } c;
  c.f = f;
  uint32_t u = c.u;
  uint32_t r = (u + 0x7FFFu + ((u >> 16) & 1u)) >> 16;
  return (ushort)r;
}

static __device__ __forceinline__ short8 pack8(floatx4 a, floatx4 b) {
  short8 t;
  t[0] = (short)f2bf(a[0]); t[1] = (short)f2bf(a[1]);
  t[2] = (short)f2bf(a[2]); t[3] = (short)f2bf(a[3]);
  t[4] = (short)f2bf(b[0]); t[5] = (short)f2bf(b[1]);
  t[6] = (short)f2bf(b[2]); t[7] = (short)f2bf(b[3]);
  return t;
}

#define MFMA16(a, b, c) __builtin_amdgcn_mfma_f32_16x16x32_bf16((a), (b), (c), 0, 0, 0)

constexpr int S_LEN = 2048;
constexpr int DH = 64;
constexpr int NH = 16;
constexpr int QBLK = 64;
constexpr int KVBLK = 64;

// Layouts (all bf16 in LDS, XOR chunk-swizzle within each 128B row: chunk ^= row&7):
//   Klds : [kv(64)][d(64)]    row-major
//   Vtlds: [d(64)][kv(64)]    transposed so PV B-frag is contiguous along kv
//   Plds : per-wave [q(16)][kv(64)]
__global__ __launch_bounds__(256, 2)
void attn_fwd(const float* __restrict__ Q, const float* __restrict__ V,
              const float* __restrict__ K, const float* __restrict__ AM,
              const float* __restrict__ SM, float* __restrict__ O)
{
  __shared__ ushort Klds[KVBLK * DH];
  __shared__ ushort Vtlds[DH * KVBLK];
  __shared__ ushort Plds[4 * 16 * KVBLK];
  __shared__ float  smlds[S_LEN];

  const int bh  = blockIdx.x;   // 0..31  (b*16+h)
  const int qt  = blockIdx.y;   // 0..31  (q tile of 64)
  const int b   = bh / NH;
  const int tid = threadIdx.x;
  const int lane = tid & 63;
  const int wave = tid >> 6;
  const int l15 = lane & 15;
  const int l4  = lane >> 4;    // 0..3

  const float* qptr  = Q  + (size_t)bh * S_LEN * DH;
  const float* kptr  = K  + (size_t)bh * S_LEN * DH;
  const float* vptr  = V  + (size_t)bh * S_LEN * DH;
  const float* amptr = AM + (size_t)b * S_LEN * S_LEN;
  const float* smptr = SM + (size_t)b * S_LEN;
  float* optr = O + (size_t)bh * S_LEN * DH;

  // stage seq_mask (fp32, whole row for this b)
  for (int i = tid; i < S_LEN / 4; i += 256)
    ((floatx4*)smlds)[i] = ((const floatx4*)smptr)[i];

  const int qb = qt * QBLK + wave * 16;   // this wave's global q-row base

  // Q fragments: lane holds Q[qb + (lane&15)][c*32 + (lane>>4)*8 + 0..7]
  short8 qf[2];
  {
    const int qrow = qb + l15;
    #pragma unroll
    for (int c = 0; c < 2; ++c) {
      const float* p = qptr + (size_t)qrow * DH + c * 32 + l4 * 8;
      floatx4 f0 = *(const floatx4*)p;
      floatx4 f1 = *(const floatx4*)(p + 4);
      qf[c] = pack8(f0, f1);
    }
  }

  float m_run[4], l_run[4];
  floatx4 oacc[4];
  #pragma unroll
  for (int r = 0; r < 4; ++r) { m_run[r] = -3.0e38f; l_run[r] = 0.f; }
  #pragma unroll
  for (int dt = 0; dt < 4; ++dt) oacc[dt] = (floatx4)(0.f);

  const int srow = tid >> 2;          // staging row 0..63
  const int scol = (tid & 3) * 16;    // staging col base
  const int cb   = (tid & 3) * 2;     // chunk base (8-ushort chunks)

  ushort* pl = &Plds[wave * 16 * KVBLK];

  for (int it = 0; it < S_LEN / KVBLK; ++it) {
    const int kv0 = it * KVBLK;

    // prefetch att_mask for this tile into registers (hides latency under staging)
    float amv[4][4];
    #pragma unroll
    for (int t = 0; t < 4; ++t)
      #pragma unroll
      for (int r = 0; r < 4; ++r)
        amv[t][r] = amptr[(size_t)(qb + l4 * 4 + r) * S_LEN + kv0 + t * 16 + l15];

    __syncthreads();   // previous iteration's LDS reads done

    // ---- stage K tile (64 kv x 64 d), bf16, swizzled ----
    {
      const float* g = kptr + (size_t)(kv0 + srow) * DH + scol;
      floatx4 f0 = ((const floatx4*)g)[0];
      floatx4 f1 = ((const floatx4*)g)[1];
      floatx4 f2 = ((const floatx4*)g)[2];
      floatx4 f3 = ((const floatx4*)g)[3];
      const int sw = srow & 7;
      *(short8*)&Klds[srow * 64 + ((cb ^ sw) * 8)]       = pack8(f0, f1);
      *(short8*)&Klds[srow * 64 + (((cb + 1) ^ sw) * 8)] = pack8(f2, f3);
    }
    // ---- stage V tile transposed: Vtlds[d][kv], bf16, swizzled ----
    {
      const float* g = vptr + (size_t)(kv0 + srow) * DH + scol;
      floatx4 f[4];
      f[0] = ((const floatx4*)g)[0];
      f[1] = ((const floatx4*)g)[1];
      f[2] = ((const floatx4*)g)[2];
      f[3] = ((const floatx4*)g)[3];
      const int kv = srow;
      #pragma unroll
      for (int i = 0; i < 16; ++i) {
        const int d = scol + i;
        const int chunk = (kv >> 3) ^ (d & 7);
        Vtlds[d * 64 + chunk * 8 + (kv & 7)] = f2bf(f[i >> 2][i & 3]);
      }
    }
    __syncthreads();

    // ---- QK^T: sacc[t] = Q(16x64) . K^T -> S[q][kv] for kv tile t ----
    floatx4 sacc[4];
    #pragma unroll
    for (int t = 0; t < 4; ++t) sacc[t] = (floatx4)(0.f);
    #pragma unroll
    for (int t = 0; t < 4; ++t) {
      #pragma unroll
      for (int c = 0; c < 2; ++c) {
        const int row = t * 16 + l15;
        const int chunk = (c * 4 + l4) ^ (row & 7);
        short8 bf = *(const short8*)&Klds[row * 64 + chunk * 8];
        sacc[t] = MFMA16(qf[c], bf, sacc[t]);
      }
    }

    // ---- online softmax (raw m,l; seq_mask only on P fed to PV) ----
    float pv[4][4];
    #pragma unroll
    for (int r = 0; r < 4; ++r) {
      float mx = -3.0e38f;
      #pragma unroll
      for (int t = 0; t < 4; ++t) {
        const float s = sacc[t][r] * 0.125f + amv[t][r];
        pv[t][r] = s;
        mx = fmaxf(mx, s);
      }
      #pragma unroll
      for (int off = 1; off < 16; off <<= 1)
        mx = fmaxf(mx, __shfl_xor(mx, off, 64));
      const float mnew = fmaxf(m_run[r], mx);
      const float fac  = __expf(m_run[r] - mnew);
      float ssum = 0.f;
      #pragma unroll
      for (int t = 0; t < 4; ++t) {
        const float e = __expf(pv[t][r] - mnew);
        pv[t][r] = e;
        ssum += e;
      }
      #pragma unroll
      for (int off = 1; off < 16; off <<= 1)
        ssum += __shfl_xor(ssum, off, 64);
      l_run[r] = l_run[r] * fac + ssum;
      m_run[r] = mnew;
      #pragma unroll
      for (int dt = 0; dt < 4; ++dt)
        oacc[dt][r] *= fac;
    }

    // ---- write P * seq_mask to wave-private LDS (bf16, swizzled) ----
    #pragma unroll
    for (int t = 0; t < 4; ++t) {
      const float smv = smlds[kv0 + t * 16 + l15];
      const int kvcol = t * 16 + l15;
      #pragma unroll
      for (int r = 0; r < 4; ++r) {
        const int qr = l4 * 4 + r;
        const int chunk = (kvcol >> 3) ^ (qr & 7);
        pl[qr * 64 + chunk * 8 + (kvcol & 7)] = f2bf(pv[t][r] * smv);
      }
    }

    // ---- PV: oacc += P(16x64) . V(64x64) ----
    #pragma unroll
    for (int c = 0; c < 2; ++c) {
      const int qr = l15;
      const int chunkA = (c * 4 + l4) ^ (qr & 7);
      short8 af = *(const short8*)&pl[qr * 64 + chunkA * 8];
      #pragma unroll
      for (int dt = 0; dt < 4; ++dt) {
        const int drow = dt * 16 + l15;
        const int chunkB = (c * 4 + l4) ^ (drow & 7);
        short8 bf = *(const short8*)&Vtlds[drow * 64 + chunkB * 8];
        oacc[dt] = MFMA16(af, bf, oacc[dt]);
      }
    }
  }

  // ---- epilogue: out = acc / l ----
  #pragma unroll
  for (int dt = 0; dt < 4; ++dt) {
    #pragma unroll
    for (int r = 0; r < 4; ++r) {
      const float inv = 1.0f / l_run[r];
      optr[(size_t)(qb + l4 * 4 + r) * DH + dt * 16 + l15] = oacc[dt][r] * inv;
    }
  }
}

extern "C" void kernel_launch(void* const* d_in, const int* in_sizes, int n_in,
                              void* d_out, int out_size, void* d_ws, size_t ws_size,
                              hipStream_t stream) {
  const float* q  = (const float*)d_in[0];
  const float* v  = (const float*)d_in[1];
  const float* k  = (const float*)d_in[2];
  const float* am = (const float*)d_in[3];
  const float* sm = (const float*)d_in[4];
  float* o = (float*)d_out;

  dim3 grid(32, 32);  // (b*h, q-tile)
  attn_fwd<<<grid, 256, 0, stream>>>(q, v, k, am, sm, o);
}

// Round 4
// 117.497 us; speedup vs baseline: 1.2923x; 1.2923x over previous
//
#include <hip/hip_runtime.h>
#include <hip/hip_bf16.h>
#include <stdint.h>

typedef __attribute__((ext_vector_type(8)))  short    short8;
typedef __attribute__((ext_vector_type(4)))  float    floatx4;
typedef __attribute__((ext_vector_type(16))) float    floatx16;
typedef __attribute__((ext_vector_type(4)))  ushort   ushortx4;

static __device__ __forceinline__ ushort f2bf(float f) {
  union { float f; uint32_t u; } c;
  c.f = f;
  uint32_t u = c.u;
  uint32_t r = (u + 0x7FFFu + ((u >> 16) & 1u)) >> 16;
  return (ushort)r;
}

static __device__ __forceinline__ uint32_t pkbf(float a, float b) {
  return (uint32_t)f2bf(a) | ((uint32_t)f2bf(b) << 16);
}

static __device__ __forceinline__ short8 pack8(floatx4 a, floatx4 b) {
  short8 t;
  t[0] = (short)f2bf(a[0]); t[1] = (short)f2bf(a[1]);
  t[2] = (short)f2bf(a[2]); t[3] = (short)f2bf(a[3]);
  t[4] = (short)f2bf(b[0]); t[5] = (short)f2bf(b[1]);
  t[6] = (short)f2bf(b[2]); t[7] = (short)f2bf(b[3]);
  return t;
}

#define MFMA32(a, b, c) __builtin_amdgcn_mfma_f32_32x32x16_bf16((a), (b), (c), 0, 0, 0)

constexpr int S_LEN = 2048;
constexpr int DH    = 64;
constexpr int QBLK  = 128;   // 4 waves x 32 q-rows
constexpr int KVBLK = 64;
constexpr int NT    = S_LEN / KVBLK;

// permlane32_swap: new_a = [a.lo32, b.lo32] ; new_b = [a.hi32, b.hi32]
static __device__ __forceinline__ void swap32(uint32_t& a, uint32_t& b, int hi) {
#if __has_builtin(__builtin_amdgcn_permlane32_swap)
  typedef int intx2 __attribute__((ext_vector_type(2)));
  intx2 r = __builtin_amdgcn_permlane32_swap((int)a, (int)b, false, false);
  a = (uint32_t)r[0]; b = (uint32_t)r[1];
#else
  uint32_t pa = (uint32_t)__shfl_xor((int)a, 32, 64);
  uint32_t pb = (uint32_t)__shfl_xor((int)b, 32, 64);
  uint32_t na = hi ? pb : a;
  uint32_t nb = hi ? b  : pa;
  a = na; b = nb;
#endif
}

__global__ __launch_bounds__(256, 2)
void attn_fwd(const float* __restrict__ Q, const float* __restrict__ V,
              const float* __restrict__ K, const float* __restrict__ AM,
              const float* __restrict__ SM, float* __restrict__ O)
{
  __shared__ ushort Kl[2][KVBLK * DH];   // [kv][d]  bf16, chunk^=(row&7) swizzle
  __shared__ ushort Vt[2][DH * KVBLK];   // [d][kv]  bf16 (plain V), swizzled
  __shared__ float  smlds[S_LEN];        // seq_mask row for this b (fp32)

  const int bh   = blockIdx.x;
  const int qt   = blockIdx.y;
  const int tid  = threadIdx.x;
  const int lane = tid & 63;
  const int wave = tid >> 6;
  const int l31  = lane & 31;
  const int hi   = lane >> 5;

  const float* qptr  = Q  + (size_t)bh * S_LEN * DH;
  const float* kptr  = K  + (size_t)bh * S_LEN * DH;
  const float* vptr  = V  + (size_t)bh * S_LEN * DH;
  const float* amptr = AM + (size_t)(bh >> 4) * S_LEN * S_LEN;
  const float* smptr = SM + (size_t)(bh >> 4) * S_LEN;
  float* optr = O + (size_t)bh * S_LEN * DH;

  // stage seq_mask once (fp32)
  for (int i = tid; i < S_LEN / 4; i += 256)
    ((floatx4*)smlds)[i] = ((const floatx4*)smptr)[i];

  const int qw = qt * QBLK + wave * 32;  // this wave's q base

  // ---- Q fragments: lane holds Q[qw + (l&31)][s*16 + hi*8 + 0..7] ----
  short8 qf[4];
  {
    const float* p = qptr + (size_t)(qw + l31) * DH + hi * 8;
    #pragma unroll
    for (int s = 0; s < 4; ++s) {
      floatx4 f0 = *(const floatx4*)(p + s * 16);
      floatx4 f1 = *(const floatx4*)(p + s * 16 + 4);
      qf[s] = pack8(f0, f1);
    }
  }

  // staging indices
  const int krow = tid >> 2;          // K: one kv row, 16 d
  const int kcol = (tid & 3) * 16;
  const int kcb  = (tid & 3) * 2;
  const int vr0  = (tid & 15) * 4;    // V: 4 kv rows, 4 d
  const int vd0  = (tid >> 4) * 4;

  floatx4 kreg[4], vreg[4];
  floatx4 amreg[2][4], amnx[2][4];

  auto LOADKV = [&](int t) {
    const float* kg = kptr + (size_t)(t * KVBLK + krow) * DH + kcol;
    #pragma unroll
    for (int j = 0; j < 4; ++j) kreg[j] = ((const floatx4*)kg)[j];
    #pragma unroll
    for (int i = 0; i < 4; ++i)
      vreg[i] = *(const floatx4*)(vptr + (size_t)(t * KVBLK + vr0 + i) * DH + vd0);
  };

  auto WRITEKV = [&](int c) {
    // K tile [kv][d]
    const int sw = krow & 7;
    *(short8*)&Kl[c][krow * 64 + ((kcb ^ sw) * 8)]       = pack8(kreg[0], kreg[1]);
    *(short8*)&Kl[c][krow * 64 + (((kcb + 1) ^ sw) * 8)] = pack8(kreg[2], kreg[3]);
    // V^T tile [d][kv] (plain bf16(V))
    #pragma unroll
    for (int d = 0; d < 4; ++d) {
      ushortx4 w;
      w[0] = f2bf(vreg[0][d]); w[1] = f2bf(vreg[1][d]);
      w[2] = f2bf(vreg[2][d]); w[3] = f2bf(vreg[3][d]);
      const int row = vd0 + d;
      const int ch  = (vr0 >> 3) ^ (row & 7);
      *(ushortx4*)&Vt[c][row * 64 + ch * 8 + (vr0 & 7)] = w;
    }
  };

  auto LOADAM = [&](int t, floatx4 am[2][4]) {
    const float* base = amptr + (size_t)(qw + l31) * S_LEN + t * KVBLK + hi * 4;
    #pragma unroll
    for (int blk = 0; blk < 2; ++blk)
      #pragma unroll
      for (int j = 0; j < 4; ++j)
        am[blk][j] = *(const floatx4*)(base + blk * 32 + j * 8);
  };

  // prologue
  LOADKV(0);
  WRITEKV(0);
  LOADAM(0, amreg);

  float m_run = -3.0e38f, l_run = 0.f;
  floatx16 oacc[2];
  #pragma unroll
  for (int db = 0; db < 2; ++db)
    #pragma unroll
    for (int r = 0; r < 16; ++r) oacc[db][r] = 0.f;

  #pragma unroll 1
  for (int t = 0; t < NT; ++t) {
    const int c = t & 1;
    __syncthreads();

    // ---- QK^T: sacc[blk] = S^T[kv][q]; lane q=l31, kv = blk*32+crow(r,hi) ----
    floatx16 sacc[2];
    #pragma unroll
    for (int blk = 0; blk < 2; ++blk) {
      #pragma unroll
      for (int r = 0; r < 16; ++r) sacc[blk][r] = 0.f;
      const int row = blk * 32 + l31;
      const int sw  = row & 7;
      #pragma unroll
      for (int s = 0; s < 4; ++s) {
        const int ch = (s * 2 + hi) ^ sw;
        short8 kf = *(const short8*)&Kl[c][row * 64 + ch * 8];
        sacc[blk] = MFMA32(kf, qf[s], sacc[blk]);
      }
    }

    // ---- scores (e-domain, round-1 numerics); lane-local row max ----
    float p[2][16];
    float pmax = -3.0e38f;
    #pragma unroll
    for (int blk = 0; blk < 2; ++blk)
      #pragma unroll
      for (int r = 0; r < 16; ++r) {
        const float v = fmaf(sacc[blk][r], 0.125f, amreg[blk][r >> 2][r & 3]);
        p[blk][r] = v;
        pmax = fmaxf(pmax, v);
      }
    pmax = fmaxf(pmax, __shfl_xor(pmax, 32, 64));

    // ---- online rescale (skip is bit-exact when no row grew: fac==1.0) ----
    if (__any(pmax > m_run)) {
      const float mnew = fmaxf(m_run, pmax);
      const float fac  = __expf(m_run - mnew);
      float fw[16];
      #pragma unroll
      for (int r = 0; r < 16; ++r)
        fw[r] = __shfl(fac, (r & 3) + 8 * (r >> 2) + 4 * hi, 64);
      #pragma unroll
      for (int db = 0; db < 2; ++db)
        #pragma unroll
        for (int r = 0; r < 16; ++r) oacc[db][r] *= fw[r];
      l_run *= fac;
      m_run = mnew;
    }

    // ---- P = exp(s - m) in fp32; denominator from UNROUNDED fp32 P ----
    float ssum = 0.f;
    #pragma unroll
    for (int blk = 0; blk < 2; ++blk)
      #pragma unroll
      for (int r = 0; r < 16; ++r) {
        const float e = __expf(p[blk][r] - m_run);
        p[blk][r] = e;
        ssum += e;
      }
    ssum += __shfl_xor(ssum, 32, 64);
    l_run += ssum;

    // ---- prefetch next tile (T14: issue early, consume at tail) ----
    const bool pf = (t + 1 < NT);
    if (pf) { LOADKV(t + 1); LOADAM(t + 1, amnx); }

    // ---- seq_mask in fragment layout (broadcast LDS reads) ----
    floatx4 smv[2][4];
    #pragma unroll
    for (int blk = 0; blk < 2; ++blk)
      #pragma unroll
      for (int j = 0; j < 4; ++j)
        smv[blk][j] = *(const floatx4*)&smlds[t * KVBLK + blk * 32 + hi * 4 + j * 8];

    // ---- (P * sm) in fp32 -> bf16 A-fragments (pack + permlane32_swap) ----
    uint32_t pw[2][2][4];
    #pragma unroll
    for (int blk = 0; blk < 2; ++blk)
      #pragma unroll
      for (int ks = 0; ks < 2; ++ks) {
        float q0 = p[blk][ks * 8 + 0] * smv[blk][ks * 2 + 0][0];
        float q1 = p[blk][ks * 8 + 1] * smv[blk][ks * 2 + 0][1];
        float q2 = p[blk][ks * 8 + 2] * smv[blk][ks * 2 + 0][2];
        float q3 = p[blk][ks * 8 + 3] * smv[blk][ks * 2 + 0][3];
        float q4 = p[blk][ks * 8 + 4] * smv[blk][ks * 2 + 1][0];
        float q5 = p[blk][ks * 8 + 5] * smv[blk][ks * 2 + 1][1];
        float q6 = p[blk][ks * 8 + 6] * smv[blk][ks * 2 + 1][2];
        float q7 = p[blk][ks * 8 + 7] * smv[blk][ks * 2 + 1][3];
        uint32_t w0 = pkbf(q0, q1);
        uint32_t w1 = pkbf(q2, q3);
        uint32_t w2 = pkbf(q4, q5);
        uint32_t w3 = pkbf(q6, q7);
        swap32(w0, w2, hi);
        swap32(w1, w3, hi);
        pw[blk][ks][0] = w0; pw[blk][ks][1] = w1;
        pw[blk][ks][2] = w2; pw[blk][ks][3] = w3;
      }

    // ---- PV: oacc[db] += (P.sm)(32q x 64kv) . V(64kv x 64d) ----
    #pragma unroll
    for (int blk = 0; blk < 2; ++blk)
      #pragma unroll
      for (int ks = 0; ks < 2; ++ks) {
        union { uint32_t u[4]; short8 s; } af;
        af.u[0] = pw[blk][ks][0]; af.u[1] = pw[blk][ks][1];
        af.u[2] = pw[blk][ks][2]; af.u[3] = pw[blk][ks][3];
        #pragma unroll
        for (int db = 0; db < 2; ++db) {
          const int row = db * 32 + l31;
          const int ch  = (blk * 4 + ks * 2 + hi) ^ (row & 7);
          short8 vf = *(const short8*)&Vt[c][row * 64 + ch * 8];
          oacc[db] = MFMA32(af.s, vf, oacc[db]);
        }
      }

    // ---- write staged t+1 into other buffer ----
    if (pf) {
      WRITEKV(c ^ 1);
      #pragma unroll
      for (int blk = 0; blk < 2; ++blk)
        #pragma unroll
        for (int j = 0; j < 4; ++j) amreg[blk][j] = amnx[blk][j];
    }
  }

  // ---- epilogue: out = oacc / l ----
  const float inv = 1.0f / l_run;
  float iw[16];
  #pragma unroll
  for (int r = 0; r < 16; ++r)
    iw[r] = __shfl(inv, (r & 3) + 8 * (r >> 2) + 4 * hi, 64);
  #pragma unroll
  for (int db = 0; db < 2; ++db)
    #pragma unroll
    for (int r = 0; r < 16; ++r) {
      const int qr = (r & 3) + 8 * (r >> 2) + 4 * hi;
      optr[(size_t)(qw + qr) * DH + db * 32 + l31] = oacc[db][r] * iw[r];
    }
}

extern "C" void kernel_launch(void* const* d_in, const int* in_sizes, int n_in,
                              void* d_out, int out_size, void* d_ws, size_t ws_size,
                              hipStream_t stream) {
  const float* q  = (const float*)d_in[0];
  const float* v  = (const float*)d_in[1];
  const float* k  = (const float*)d_in[2];
  const float* am = (const float*)d_in[3];
  const float* sm = (const float*)d_in[4];
  float* o = (float*)d_out;

  dim3 grid(32, S_LEN / QBLK);  // (b*h, q-tile of 128)
  attn_fwd<<<grid, 256, 0, stream>>>(q, v, k, am, sm, o);
}